// Round 4
// baseline (204.431 us; speedup 1.0000x reference)
//
#include <hip/hip_runtime.h>

// SNN spike layer: causal alpha-PSP FIR conv (taps 1..76; srm[0]==0 exactly)
// + sequential refractory threshold scan.
//
// Structure: 32 neurons/block x 8 time-splits (7x40 + 1x20) = 256 threads,
// 2048 blocks. LDS u-stage = 32*301*4 = 38.5 KB; __launch_bounds__(256,3)
// -> <=170 VGPR budget -> 3 blocks/CU = 12 waves/CU = 3 waves/SIMD.
// Round-2 evidence: VGPR_Count=124 < ~145 live => compiler SANK the chunk
// prefetch below the conv, exposing full load latency (VALUBusy 38%).
// Fixes: (a) 3 waves/SIMD + 170-VGPR budget; (b) sched_barrier(0) pins the
// prefetch issue above the 1520-FMA conv.
// Round-3 crash fix: QT=40 < KT=76 means the q==1 split's pre-window starts
// at t=-36 -> was reading 144 B before the buffer (fault). Now: q==0 -> 76
// zeros; q==1 -> 36 zeros + x[0..39]; q>=2 -> full 76-float load (byte
// offset 160q-304 == 0 mod 16, aligned for all q).
//
// Bit-exactness invariant (absmax must stay 0.0): each u[t] accumulates taps
// j=1..76 ascending via a single fmaf chain (srm[0]==0 dropped: fmaf(0,x,u)
// ==u); zero history entries are fmaf(w,0,u) no-ops; scan step identical to
// the verified baseline. No reassociation anywhere.

#define T_LEN 300
#define KS 77              // srm kernel length (alpha, tau=10, eps_tol=0.01)
#define KT 76              // effective taps j = 1..76 (srm[0] == 0 exactly)
#define KR 10              // ref kernel tail length (K_ref=11 -> 10 pending)
#define THETA_V 10.0f
#define NPB 32             // neurons per block
#define SPL 8              // time splits per neuron
#define QT 40              // split stride: q=0..6 cover 40 outputs, q=7 covers 20
#define CH 20              // outputs per conv inner pass
#define ROWP 301           // LDS row pad: 301 mod 32 = 13, gcd=1 -> conflict-free

__global__ __launch_bounds__(256, 3) void spike_layer_kernel(
    const float* __restrict__ spike_in,
    const float* __restrict__ srm, int srm_len,
    const float* __restrict__ refk, int ref_len,
    float* __restrict__ out, int B)
{
    __shared__ float u_lds[NPB * ROWP];   // 38528 B

    const int tid = threadIdx.x;
    const int n   = tid & (NPB - 1);      // neuron within block
    const int q   = tid >> 5;             // time-split 0..7 (half-wave uniform)
    const int neuron = blockIdx.x * NPB + n;
    const bool valid = (neuron < B);

    const float* row  = spike_in + (size_t)neuron * T_LEN;
    float*       urow = &u_lds[n * ROWP];

    // srm taps (uniform-address loads -> scalarized). Tap 0 skipped: exactly 0.
    float srm_r[KS];
#pragma unroll
    for (int i = 1; i < KS; ++i) srm_r[i] = (i < srm_len) ? srm[i] : 0.0f;

    const int t0  = q * QT;                     // 0,40,...,280
    const int nch = (q < SPL - 1) ? (QT / CH)   // 2 chunks of 20
                                  : ((T_LEN - (SPL - 1) * QT) / CH);  // 1

    // history window: hist[i] = x[t0 + i - KT]; tail [KT..KT+CH) = current chunk
    float hist[KT + CH];
    if (q == 0 || !valid) {
#pragma unroll
        for (int i = 0; i < KT; ++i) hist[i] = 0.0f;          // t < 0 -> no spikes
    } else if (q == 1) {
        // pre-window spans t=-36..39: first 36 are t<0 -> zero; then x[0..39].
#pragma unroll
        for (int i = 0; i < KT - QT; ++i) hist[i] = 0.0f;     // 36 zeros
        const float4* p = (const float4*)row;                 // row is 16B-aligned
#pragma unroll
        for (int i = 0; i < QT / 4; ++i) {                    // x[0..39] -> hist[36..75]
            float4 v = p[i];
            hist[KT - QT + 4*i + 0] = v.x; hist[KT - QT + 4*i + 1] = v.y;
            hist[KT - QT + 4*i + 2] = v.z; hist[KT - QT + 4*i + 3] = v.w;
        }
    } else {
        // full pre-window x[t0-76..t0-1]; byte offset 160q-304 == 0 mod 16.
        const float4* p = (const float4*)(row + t0 - KT);
#pragma unroll
        for (int i = 0; i < KT / 4; ++i) {
            float4 v = p[i];
            hist[4*i+0] = v.x; hist[4*i+1] = v.y; hist[4*i+2] = v.z; hist[4*i+3] = v.w;
        }
    }

    // preload chunk 0 (byte offset 160q, 16B-aligned)
    float nxt[CH];
    if (valid) {
        const float4* p = (const float4*)(row + t0);
#pragma unroll
        for (int i = 0; i < CH / 4; ++i) {
            float4 v = p[i];
            nxt[4*i+0] = v.x; nxt[4*i+1] = v.y; nxt[4*i+2] = v.z; nxt[4*i+3] = v.w;
        }
    } else {
#pragma unroll
        for (int i = 0; i < CH; ++i) nxt[i] = 0.0f;
    }

#pragma unroll 1           // keep the ~1.7k-inst body I-cache resident
    for (int c0 = 0; c0 < nch; ++c0) {
        // install current chunk into window tail (consumes nxt -> frees regs)
#pragma unroll
        for (int i = 0; i < CH; ++i) hist[KT + i] = nxt[i];

        // prefetch next chunk; sched_barrier pins the load ISSUE here so its
        // latency hides under the 1520-FMA conv (round-2 evidence: without it
        // the scheduler sinks the loads below the conv to save registers).
        if (c0 + 1 < nch && valid) {
            const float4* p = (const float4*)(row + t0 + (c0 + 1) * CH);
#pragma unroll
            for (int i = 0; i < CH / 4; ++i) {
                float4 v = p[i];
                nxt[4*i+0] = v.x; nxt[4*i+1] = v.y; nxt[4*i+2] = v.z; nxt[4*i+3] = v.w;
            }
        }
        __builtin_amdgcn_sched_barrier(0);

        // conv: u[t0+20*c0+c] = sum_{j=1}^{76} srm[j]*x[..-j]; 20 indep chains
        float u[CH];
#pragma unroll
        for (int c = 0; c < CH; ++c) u[c] = 0.0f;
#pragma unroll
        for (int j = 1; j < KS; ++j) {
            const float w = srm_r[j];
#pragma unroll
            for (int c = 0; c < CH; ++c)
                u[c] = fmaf(w, hist[KT + c - j], u[c]);
        }

        // u -> LDS (lanes hit distinct rows: 301n mod 32 all distinct)
        float* up = urow + t0 + c0 * CH;
#pragma unroll
        for (int c = 0; c < CH; ++c) up[c] = u[c];

        // slide window by CH (skip on last chunk)
        if (c0 + 1 < nch) {
#pragma unroll
            for (int i = 0; i < KT; ++i) hist[i] = hist[i + CH];
        }
    }

    __syncthreads();

    // ---- scan phase: lanes 0..31 of wave 0 (lane n scans neuron n) ----
    if (tid >= NPB || !valid) return;

    // refractory tail: ref_kernel[1..], contributions to t+1..t+KR
    float rt[KR];
#pragma unroll
    for (int i = 0; i < KR; ++i) rt[i] = (i + 1 < ref_len) ? refk[i + 1] : 0.0f;

    // pending queue, circular: logical pend[i] lives at pend[(r+i)%KR], r = t%KR
    float pend[KR];
#pragma unroll
    for (int i = 0; i < KR; ++i) pend[i] = 0.0f;

    float* orow = out + (size_t)neuron * T_LEN;

#pragma unroll 1
    for (int cb = 0; cb < T_LEN / CH; ++cb) {
        // batch 20 independent LDS reads (conflict-free), one waitcnt
        float uv[CH];
#pragma unroll
        for (int c = 0; c < CH; ++c) uv[c] = urow[cb * CH + c];

        float so[CH];
#pragma unroll
        for (int c = 0; c < CH; ++c) {
            const int r = c % KR;      // compile-time (CH == 2*KR)
            float u_eff = uv[c] + pend[r];
            float s = (u_eff >= THETA_V) ? 1.0f : 0.0f;
#pragma unroll
            for (int i = 0; i < KR - 1; ++i)
                pend[(r + 1 + i) % KR] = fmaf(s, rt[i], pend[(r + 1 + i) % KR]);
            pend[r] = s * rt[KR - 1];  // consumed slot becomes logical tail
            so[c] = s;                 // s / TS, TS == 1
        }

        float4* op = (float4*)(orow + cb * CH);
#pragma unroll
        for (int i = 0; i < CH / 4; ++i) {
            float4 v;
            v.x = so[4*i+0]; v.y = so[4*i+1]; v.z = so[4*i+2]; v.w = so[4*i+3];
            op[i] = v;
        }
    }
}

extern "C" void kernel_launch(void* const* d_in, const int* in_sizes, int n_in,
                              void* d_out, int out_size, void* d_ws, size_t ws_size,
                              hipStream_t stream) {
    const float* spike_in = (const float*)d_in[0];
    const float* srm      = (const float*)d_in[1];
    const float* refk     = (const float*)d_in[2];
    float* out = (float*)d_out;

    int srm_len = in_sizes[1];
    int ref_len = in_sizes[2];
    int B = in_sizes[0] / T_LEN;   // 65536 neurons

    int block = 256;                       // 32 neurons x 8 time-splits
    int grid = (B + NPB - 1) / NPB;        // 2048 blocks
    spike_layer_kernel<<<grid, block, 0, stream>>>(spike_in, srm, srm_len,
                                                   refk, ref_len, out, B);
}

// Round 5
// 200.814 us; speedup vs baseline: 1.0180x; 1.0180x over previous
//
#include <hip/hip_runtime.h>

// SNN spike layer: causal alpha-PSP FIR conv (taps 1..76; srm[0]==0 exactly)
// + sequential refractory threshold scan.
//
// Round-5 structure: the register-sliding-window approach is dead -- four
// rounds of counters show the allocator refuses to hold a 96-float hist
// window (allocs 84-124 VGPR, spills to scratch: R0/R1 ~43MB, R4 ~26MB of
// WRITE_SIZE inflation). This build reads conv operands from LDS in tap-bands
// so the per-thread live set is ~75 VGPR:
//   - block = 16 neurons x 16 time-splits (15 active, 20 outputs each)
//   - stage block input (contiguous 4800 floats, perfectly coalesced) into
//     LDS rows: 80-float zero front-pad + 300 data, stride 380 floats
//     (380 % 32 = 28 -> uniform bank spread; mult of 4 -> b128-aligned)
//   - conv per thread: 5 bands of <=16 taps; per band 8-9 ds_read_b128 into
//     a 36-float window, 320 FMAs; u[20] accumulates across bands
//   - u rides registers across a barrier, then OVERWRITES the x region
//     (x fully consumed) -> LDS stays 24.3 KB -> up to 6 blocks/CU
//   - scan: lanes 0..15 of wave 0, same verified code, reads u from LDS
//
// Bit-exactness invariant (absmax must stay 0.0): each u[t] accumulates taps
// j=1..76 ascending in ONE fmaf chain (bands are j=1..16,17..32,...,65..76 in
// order); front-pad zeros give fmaf(w,0,u)==u, identical to the verified
// kernels' zero-history no-ops; scan step identical. No reassociation.

#define T_LEN 300
#define KS 77              // srm kernel length
#define KR 10              // ref kernel tail length (K_ref=11 -> 10 pending)
#define THETA_V 10.0f
#define NPB 16             // neurons per block
#define CH 20              // outputs per thread
#define SPL 15             // active splits: 15 * 20 = 300
#define PADF 80            // zero front-pad floats per LDS row
#define ROWF 380           // LDS row stride floats (80 + 300); %32=28, %4=0

__global__ __launch_bounds__(256, 4) void spike_layer_kernel(
    const float* __restrict__ spike_in,
    const float* __restrict__ srm, int srm_len,
    const float* __restrict__ refk, int ref_len,
    float* __restrict__ out, int B)
{
    __shared__ float xs[NPB * ROWF];   // 24320 B -> LDS allows 6 blocks/CU

    const int tid = threadIdx.x;
    const int n   = tid & (NPB - 1);   // neuron within block
    const int s   = tid >> 4;          // time-split 0..15 (15 = idle in conv)

    // ---- stage: zero the 80-float front pads (16 rows x 20 float4) ----
    {
        const float4 z = {0.0f, 0.0f, 0.0f, 0.0f};
        int i = tid;                   // 0..255 covers 256 of 320
        {
            int r = i / 20, o = i % 20;
            *(float4*)&xs[r * ROWF + 4 * o] = z;
        }
        i = tid + 256;                 // 256..319 (tid < 64)
        if (i < NPB * (PADF / 4)) {
            int r = i / 20, o = i % 20;
            *(float4*)&xs[r * ROWF + 4 * o] = z;
        }
    }

    // ---- stage: input rows. Block's 16 neurons are CONTIGUOUS in global
    // (4800 floats = 1200 float4), so loads are perfectly coalesced. ----
    {
        const int rowf4 = T_LEN / 4;                   // 75 float4 per row
        const int blkf4 = NPB * rowf4;                 // 1200
        const long long totf4 = (long long)B * rowf4;  // global guard
        const long long jg0 = (long long)blockIdx.x * blkf4;
        const float4* gin = (const float4*)spike_in;
#pragma unroll
        for (int k = 0; k < 5; ++k) {
            int j = tid + 256 * k;
            if (j < blkf4 && jg0 + j < totf4) {
                float4 v = gin[jg0 + j];
                int r = j / rowf4, o = j % rowf4;
                *(float4*)&xs[r * ROWF + PADF + 4 * o] = v;
            }
        }
    }

    // srm taps (uniform-address loads -> scalarized to SGPRs). Tap 0 == 0.0.
    float srm_r[KS];
#pragma unroll
    for (int i = 1; i < KS; ++i) srm_r[i] = (i < srm_len) ? srm[i] : 0.0f;

    __syncthreads();

    // ---- conv: u[t0+c] = sum_{j=1}^{76} srm[j] * x[t0+c-j], c in [0,20) ----
    const int t0 = s * CH;
    const float* xrow = &xs[n * ROWF];

    float u[CH];
#pragma unroll
    for (int c = 0; c < CH; ++c) u[c] = 0.0f;

    if (s < SPL) {
        // bands 0..3: taps j = 16b+1 .. 16b+16; window = x[t0-16(b+1) .. t0+19]
#pragma unroll
        for (int b = 0; b < 4; ++b) {
            const int base = t0 + PADF - 16 * (b + 1);  // LDS idx of window[0]
            float xw[36];
#pragma unroll
            for (int i = 0; i < 9; ++i) {
                float4 v = *(const float4*)&xrow[base + 4 * i];
                xw[4*i+0] = v.x; xw[4*i+1] = v.y; xw[4*i+2] = v.z; xw[4*i+3] = v.w;
            }
            // xw[m] = x[t0 - 16(b+1) + m]; tap j = 16b+d -> operand xw[c+16-d]
#pragma unroll
            for (int d = 1; d <= 16; ++d) {
                const float w = srm_r[16 * b + d];
#pragma unroll
                for (int c = 0; c < CH; ++c)
                    u[c] = fmaf(w, xw[c + 16 - d], u[c]);
            }
        }
        // band 4: taps j = 65..76; window = x[t0-76 .. t0-45] (32 floats)
        {
            const int base = t0 + 4;                    // = t0 + 80 - 76
            float xw[32];
#pragma unroll
            for (int i = 0; i < 8; ++i) {
                float4 v = *(const float4*)&xrow[base + 4 * i];
                xw[4*i+0] = v.x; xw[4*i+1] = v.y; xw[4*i+2] = v.z; xw[4*i+3] = v.w;
            }
            // xw[m] = x[t0 - 76 + m]; tap j -> operand xw[c + 76 - j]
#pragma unroll
            for (int d = 65; d <= 76; ++d) {
                const float w = srm_r[d];
#pragma unroll
                for (int c = 0; c < CH; ++c)
                    u[c] = fmaf(w, xw[c + 76 - d], u[c]);
            }
        }
    }

    // all conv reads of xs complete before u overwrites it
    __syncthreads();

    if (s < SPL) {
#pragma unroll
        for (int i = 0; i < CH / 4; ++i) {
            float4 v;
            v.x = u[4*i+0]; v.y = u[4*i+1]; v.z = u[4*i+2]; v.w = u[4*i+3];
            *(float4*)&xs[n * ROWF + PADF + t0 + 4 * i] = v;
        }
    }

    __syncthreads();

    // ---- scan: lanes 0..15 of wave 0 (lane n scans neuron n) ----
    const int neuron = blockIdx.x * NPB + n;
    if (tid >= NPB || neuron >= B) return;

    float rt[KR];
#pragma unroll
    for (int i = 0; i < KR; ++i) rt[i] = (i + 1 < ref_len) ? refk[i + 1] : 0.0f;

    float pend[KR];
#pragma unroll
    for (int i = 0; i < KR; ++i) pend[i] = 0.0f;

    float* orow = out + (size_t)neuron * T_LEN;
    const float* ur = &xs[n * ROWF + PADF];

#pragma unroll 1
    for (int cb = 0; cb < T_LEN / CH; ++cb) {
        float uv[CH];
#pragma unroll
        for (int i = 0; i < CH / 4; ++i) {
            float4 v = *(const float4*)&ur[cb * CH + 4 * i];
            uv[4*i+0] = v.x; uv[4*i+1] = v.y; uv[4*i+2] = v.z; uv[4*i+3] = v.w;
        }

        float so[CH];
#pragma unroll
        for (int c = 0; c < CH; ++c) {
            const int r = c % KR;      // compile-time (CH == 2*KR)
            float u_eff = uv[c] + pend[r];
            float sp = (u_eff >= THETA_V) ? 1.0f : 0.0f;
#pragma unroll
            for (int i = 0; i < KR - 1; ++i)
                pend[(r + 1 + i) % KR] = fmaf(sp, rt[i], pend[(r + 1 + i) % KR]);
            pend[r] = sp * rt[KR - 1]; // consumed slot becomes logical tail
            so[c] = sp;                // s / TS, TS == 1
        }

        float4* op = (float4*)(orow + cb * CH);
#pragma unroll
        for (int i = 0; i < CH / 4; ++i) {
            float4 v;
            v.x = so[4*i+0]; v.y = so[4*i+1]; v.z = so[4*i+2]; v.w = so[4*i+3];
            op[i] = v;
        }
    }
}

extern "C" void kernel_launch(void* const* d_in, const int* in_sizes, int n_in,
                              void* d_out, int out_size, void* d_ws, size_t ws_size,
                              hipStream_t stream) {
    const float* spike_in = (const float*)d_in[0];
    const float* srm      = (const float*)d_in[1];
    const float* refk     = (const float*)d_in[2];
    float* out = (float*)d_out;

    int srm_len = in_sizes[1];
    int ref_len = in_sizes[2];
    int B = in_sizes[0] / T_LEN;   // 65536 neurons

    int block = 256;                      // 16 neurons x 16 time-splits
    int grid = (B + NPB - 1) / NPB;       // 4096 blocks
    spike_layer_kernel<<<grid, block, 0, stream>>>(spike_in, srm, srm_len,
                                                   refk, ref_len, out, B);
}

// Round 7
// 178.375 us; speedup vs baseline: 1.1461x; 1.1258x over previous
//
#include <hip/hip_runtime.h>

// SNN spike layer: causal alpha-PSP FIR conv (taps 1..76; srm[0]==0 exactly)
// + sequential refractory threshold scan.
//
// Round-7 = round-6 resubmitted verbatim (bench infra failed; kernel untested).
// Structure: fastest verified frame (R0: 1 thread/neuron, 15 chunks of 20,
// inline scan) with the KEY fix: the input is BINARY (spike_in in {0.0, 1.0}
// exactly), so the 96-element history window is 96 BITS in 3 VGPRs, not 96
// f32 VGPRs. Removes the allocator's spill trigger (R0/R1/R4: 84-124 VGPR
// alloc'd vs ~145 live -> 26-43 MB scratch leak) and R5's LDS bank conflicts
// (1.05e7 cycles) simultaneously:
//   - window slide     : 3 v_alignbit  (was 76 movs or LDS traffic)
//   - operand regen    : per 16-tap band, unpack 35 bits -> f32 (bfe+cvt)
//   - conv             : same 1520-FMA / 20-chain chunk as every passing round
//   - scan             : identical verified code, inline, full thread count
// No LDS, no barriers, no cross-thread coupling.
//
// Bit-exactness invariant (absmax must stay 0.0): operands are exactly
// 0.0/1.0; (float)((bits>>p)&1) reproduces them exactly; each u[t] still
// accumulates taps j=1..76 ascending in ONE fmaf chain; scan step identical.
// No reassociation anywhere.

#define T_LEN 300
#define CH 20
#define NCHUNK 15          // 15 * 20 == 300 exactly
#define KS 77              // srm kernel length (alpha, tau=10, eps_tol=0.01)
#define KR 10              // ref kernel tail length (K_ref=11 -> 10 pending)
#define THETA_V 10.0f

__global__ __launch_bounds__(256, 1) void spike_layer_kernel(
    const float* __restrict__ spike_in,
    const float* __restrict__ srm, int srm_len,
    const float* __restrict__ refk, int ref_len,
    float* __restrict__ out, int B)
{
    int b = blockIdx.x * blockDim.x + threadIdx.x;
    if (b >= B) return;

    const float* row  = spike_in + (size_t)b * T_LEN;
    float*       orow = out      + (size_t)b * T_LEN;

    // srm taps (wave-uniform loads -> scalarized to SGPRs). Tap 0 == 0.0.
    float srm_r[KS];
#pragma unroll
    for (int i = 1; i < KS; ++i) srm_r[i] = (i < srm_len) ? srm[i] : 0.0f;

    // refractory tail: ref_kernel[1..], contributions to t+1..t+KR
    float rt[KR];
#pragma unroll
    for (int i = 0; i < KR; ++i) rt[i] = (i + 1 < ref_len) ? refk[i + 1] : 0.0f;

    float pend[KR];
#pragma unroll
    for (int i = 0; i < KR; ++i) pend[i] = 0.0f;

    // 96-bit history window: bit i = x[t0 - 76 + i] for current chunk base t0.
    unsigned w0 = 0, w1 = 0, w2 = 0;   // t < 0 -> no spikes

    // preload chunk 0
    float nxt[CH];
    {
        const float4* p = (const float4*)row;
#pragma unroll
        for (int i = 0; i < CH / 4; ++i) {
            float4 v = p[i];
            nxt[4*i+0] = v.x; nxt[4*i+1] = v.y; nxt[4*i+2] = v.z; nxt[4*i+3] = v.w;
        }
    }

#pragma unroll 1           // keep the ~2.2k-inst body I-cache resident
    for (int ch = 0; ch < NCHUNK; ++ch) {
        // pack current chunk to bits: x is exactly 0.0f or 1.0f, so IEEE
        // bit 30 (0x3F800000 vs 0x00000000) IS the spike bit.
        unsigned nb = 0;
#pragma unroll
        for (int i = 0; i < CH; ++i)
            nb |= ((__float_as_uint(nxt[i]) >> 30) & 1u) << i;

        // slide window by 20, install current chunk at bits 76..95
        w0 = (w0 >> 20) | (w1 << 12);
        w1 = (w1 >> 20) | (w2 << 12);
        w2 = (w2 >> 20) | (nb << 12);

        // prefetch next chunk; sched_barrier pins the load issue above the
        // conv so its latency hides under the 1520 FMAs (round-2 lesson).
        if (ch + 1 < NCHUNK) {
            const float4* p = (const float4*)(row + (ch + 1) * CH);
#pragma unroll
            for (int i = 0; i < CH / 4; ++i) {
                float4 v = p[i];
                nxt[4*i+0] = v.x; nxt[4*i+1] = v.y; nxt[4*i+2] = v.z; nxt[4*i+3] = v.w;
            }
        }
        __builtin_amdgcn_sched_barrier(0);

        // conv: u[t0+c] = sum_{j=1}^{76} srm[j] * x[t0+c-j]; operand bit index
        // in window = 76 + c - j. 20 independent FMA chains, taps ascending.
        float u[CH];
#pragma unroll
        for (int c = 0; c < CH; ++c) u[c] = 0.0f;

        // bands 0..3: taps j = 16*bb+1 .. 16*bb+16; window bits [60-16bb, 94-16bb]
#pragma unroll
        for (int bb = 0; bb < 4; ++bb) {
            const int base = 60 - 16 * bb;
            float xw[35];                       // xw[m] = bit(base + m) as f32
#pragma unroll
            for (int m = 0; m < 35; ++m) {
                const int p = base + m;         // compile-time
                const unsigned reg = (p < 32) ? w0 : ((p < 64) ? w1 : w2);
                xw[m] = (float)((reg >> (p & 31)) & 1u);   // v_bfe + v_cvt
            }
#pragma unroll
            for (int d = 1; d <= 16; ++d) {
                const float wt = srm_r[16 * bb + d];
#pragma unroll
                for (int c = 0; c < CH; ++c)
                    u[c] = fmaf(wt, xw[16 - d + c], u[c]);
            }
        }
        // band 4: taps j = 65..76; window bits 0..30 (all in w0)
        {
            float xw[31];
#pragma unroll
            for (int m = 0; m < 31; ++m)
                xw[m] = (float)((w0 >> m) & 1u);
#pragma unroll
            for (int d = 1; d <= 12; ++d) {
                const float wt = srm_r[64 + d];
#pragma unroll
                for (int c = 0; c < CH; ++c)
                    u[c] = fmaf(wt, xw[12 - d + c], u[c]);
            }
        }

        // sequential threshold scan (verified code), store float4 every 4
        float4 sv;
#pragma unroll
        for (int c = 0; c < CH; ++c) {
            const int r = c % KR;      // compile-time (CH == 2*KR)
            float u_eff = u[c] + pend[r];
            float s = (u_eff >= THETA_V) ? 1.0f : 0.0f;
#pragma unroll
            for (int i = 0; i < KR - 1; ++i)
                pend[(r + 1 + i) % KR] = fmaf(s, rt[i], pend[(r + 1 + i) % KR]);
            pend[r] = s * rt[KR - 1];  // consumed slot becomes logical tail
            if ((c & 3) == 0) sv.x = s;
            else if ((c & 3) == 1) sv.y = s;
            else if ((c & 3) == 2) sv.z = s;
            else {
                sv.w = s;
                *(float4*)(orow + ch * CH + (c - 3)) = sv;
            }
        }
    }
}

extern "C" void kernel_launch(void* const* d_in, const int* in_sizes, int n_in,
                              void* d_out, int out_size, void* d_ws, size_t ws_size,
                              hipStream_t stream) {
    const float* spike_in = (const float*)d_in[0];
    const float* srm      = (const float*)d_in[1];
    const float* refk     = (const float*)d_in[2];
    float* out = (float*)d_out;

    int srm_len = in_sizes[1];
    int ref_len = in_sizes[2];
    int B = in_sizes[0] / T_LEN;   // 65536 neurons

    int block = 256;
    int grid = (B + block - 1) / block;
    spike_layer_kernel<<<grid, block, 0, stream>>>(spike_in, srm, srm_len,
                                                   refk, ref_len, out, B);
}